// Round 2
// baseline (501.007 us; speedup 1.0000x reference)
//
#include <hip/hip_runtime.h>
#include <math.h>

#define N_NODES 30000
#define N_EDGES 240000
#define DMODEL 256
#define NETYPES 8
#define NGRAPHS 64
#define NLAYERS 3

typedef __attribute__((ext_vector_type(8))) short short8;
typedef __attribute__((ext_vector_type(4))) float f32x4;

// ---- bf16 split helpers (round-to-nearest-even) ----
__device__ __forceinline__ unsigned short f2bf(float f) {
  union { float f; unsigned u; } v; v.f = f;
  unsigned r = v.u + 0x7FFF + ((v.u >> 16) & 1);
  return (unsigned short)(r >> 16);
}
__device__ __forceinline__ float bf2f(unsigned short h) {
  union { unsigned u; float f; } v; v.u = ((unsigned)h) << 16;
  return v.f;
}

__device__ __forceinline__ void async_g2l(const unsigned short* g, unsigned short* l) {
  __builtin_amdgcn_global_load_lds(
      (const __attribute__((address_space(1))) void*)g,
      (__attribute__((address_space(3))) void*)l, 16, 0, 0);
}

// ---------------- CSR build (by destination node) ----------------
__global__ void k_count_deg(const int* __restrict__ dst, int* __restrict__ deg) {
  int e = blockIdx.x * blockDim.x + threadIdx.x;
  if (e < N_EDGES) atomicAdd(&deg[dst[e]], 1);
}

__global__ __launch_bounds__(1024) void k_scan(const int* __restrict__ deg,
                                               int* __restrict__ rowstart,
                                               int* __restrict__ cursor) {
  const int C = 30;
  int tid = threadIdx.x;
  int base = tid * C;
  int vals[C];
  int sum = 0;
#pragma unroll
  for (int j = 0; j < C; ++j) {
    int idx = base + j;
    int v = (idx < N_NODES) ? deg[idx] : 0;
    vals[j] = sum;
    sum += v;
  }
  int lane = tid & 63, wv = tid >> 6;
  int s = sum;
#pragma unroll
  for (int off = 1; off < 64; off <<= 1) {
    int t2 = __shfl_up(s, off);
    if (lane >= off) s += t2;
  }
  __shared__ int wsum[16];
  if (lane == 63) wsum[wv] = s;
  __syncthreads();
  if (tid == 0) {
    int a = 0;
#pragma unroll
    for (int i = 0; i < 16; ++i) { int t2 = wsum[i]; wsum[i] = a; a += t2; }
    rowstart[N_NODES] = a;
  }
  __syncthreads();
  int texcl = wsum[wv] + (s - sum);
#pragma unroll
  for (int j = 0; j < C; ++j) {
    int idx = base + j;
    if (idx < N_NODES) {
      int p = texcl + vals[j];
      rowstart[idx] = p;
      cursor[idx]   = p;
    }
  }
}

__global__ void k_scatter(const int* __restrict__ src, const int* __restrict__ dst,
                          const int* __restrict__ etype, int* __restrict__ cursor,
                          int* __restrict__ packed) {
  int e = blockIdx.x * blockDim.x + threadIdx.x;
  if (e < N_EDGES) {
    int p = atomicAdd(&cursor[dst[e]], 1);
    packed[p] = src[e] * NETYPES + etype[e];
  }
}

// ---------------- weight transpose (coalesced, LDS tile), bf16 hi only ----------
__global__ __launch_bounds__(256) void k_cvt_w(
    const float* __restrict__ Wq, const float* __restrict__ Wk, const float* __restrict__ Wv,
    unsigned short* __restrict__ wthi) {
  __shared__ float tile[32][33];
  int k0 = blockIdx.x * 32;          // 0..224
  int n0g = blockIdx.y * 32;         // 0..736
  int l = blockIdx.z;
  int which = n0g >> 8;
  int col0 = n0g & 255;
  const float* W = (which == 0) ? Wq : ((which == 1) ? Wk : Wv);
  int c = threadIdx.x & 31, r = threadIdx.x >> 5;
#pragma unroll
  for (int rr = 0; rr < 4; ++rr) {
    int kk = r + rr * 8;
    tile[kk][c] = W[(size_t)l * 65536 + (size_t)(k0 + kk) * 256 + col0 + c];
  }
  __syncthreads();
  int kk = threadIdx.x & 31, nn0 = threadIdx.x >> 5;
#pragma unroll
  for (int rr = 0; rr < 4; ++rr) {
    int nn = nn0 + rr * 8;
    wthi[((size_t)l * 768 + n0g + nn) * 256 + k0 + kk] = f2bf(tile[kk][nn]);
  }
}

__global__ void k_cvt_b(const float* __restrict__ bq, const float* __restrict__ bk,
                        const float* __restrict__ bv, float* __restrict__ bcat) {
  int idx = blockIdx.x * 256 + threadIdx.x;
  if (idx >= NLAYERS * 768) return;
  int n = idx % 768, l = idx / 768;
  int which = n >> 8, col = n & 255;
  const float* b = (which == 0) ? bq : ((which == 1) ? bk : bv);
  bcat[idx] = b[l * 256 + col];
}

__global__ void k_cvt_x(const float* __restrict__ x, unsigned short* __restrict__ xhi,
                        unsigned short* __restrict__ xlo) {
  int i = blockIdx.x * 256 + threadIdx.x;
  if (i < N_NODES * 256) {
    float v = x[i];
    unsigned short h = f2bf(v);
    xhi[i] = h;
    xlo[i] = f2bf(v - bf2f(h));
  }
}

// ---------------- split-bf16 MFMA GEMM, 2-term (Ahi*Bhi + Alo*Bhi) ----------
// XCD-grouped swizzle (6 col-blocks of a row-tile share one XCD's L2) +
// double-buffered LDS with counted vmcnt (no vmcnt(0) drain inside the loop).
__global__ __launch_bounds__(256) void k_gemm_mfma(
    const unsigned short* __restrict__ Ahi, const unsigned short* __restrict__ Alo,
    const unsigned short* __restrict__ Bhi,
    const float* __restrict__ bcat, float* __restrict__ qbuf,
    unsigned short* __restrict__ kv) {
  __shared__ unsigned short smem[2 * 12288];

  int tid = threadIdx.x;
  int lane = tid & 63, wave = tid >> 6;
  int bx = blockIdx.x;
  int xcd = bx & 7, slot = bx >> 3;
  int rt = xcd + (slot / 6) * 8;
  if (rt >= 235) return;
  int row0 = rt * 128;
  int n0 = (slot % 6) * 128;
  int wm = (wave >> 1) * 64, wn = (wave & 1) * 64;
  int quad = lane >> 4, l16 = lane & 15;
  int chunk = lane & 3;
  int srow = wave * 32 + (lane >> 2);

  f32x4 acc[4][4];
#pragma unroll
  for (int i = 0; i < 4; ++i)
#pragma unroll
    for (int j = 0; j < 4; ++j) acc[i][j] = (f32x4)(0.f);

  auto STAGE = [&](int k0, int b) {
    unsigned short* s = smem + b * 12288;
#pragma unroll
    for (int j = 0; j < 2; ++j) {
      int r = srow + j * 16;
      int ldsoff = wave * 1024 + j * 512;
      int garA = row0 + r; if (garA >= N_NODES) garA = N_NODES - 1;
      size_t aoff = (size_t)garA * 256 + k0 + chunk * 8;
      async_g2l(Ahi + aoff, s + ldsoff);
      async_g2l(Alo + aoff, s + 4096 + ldsoff);
      size_t boff = (size_t)(n0 + r) * 256 + k0 + chunk * 8;
      async_g2l(Bhi + boff, s + 8192 + ldsoff);
    }
  };

  STAGE(0, 0);
#pragma unroll
  for (int k = 0; k < 8; ++k) {
    int cur = k & 1;
    if (k < 7) {
      STAGE((k + 1) * 32, cur ^ 1);
      asm volatile("s_waitcnt vmcnt(6)" ::: "memory");
    } else {
      asm volatile("s_waitcnt vmcnt(0)" ::: "memory");
    }
    __builtin_amdgcn_s_barrier();

    const unsigned short* sAhi = smem + cur * 12288;
    const unsigned short* sAlo = sAhi + 4096;
    const unsigned short* sBhi = sAhi + 8192;
    short8 ah[4], al[4], bh[4];
#pragma unroll
    for (int i = 0; i < 4; ++i) {
      int off = (wm + i * 16 + l16) * 32 + quad * 8;
      ah[i] = *(const short8*)(sAhi + off);
      al[i] = *(const short8*)(sAlo + off);
    }
#pragma unroll
    for (int j = 0; j < 4; ++j) {
      int off = (wn + j * 16 + l16) * 32 + quad * 8;
      bh[j] = *(const short8*)(sBhi + off);
    }
#pragma unroll
    for (int i = 0; i < 4; ++i)
#pragma unroll
      for (int j = 0; j < 4; ++j) {
        acc[i][j] = __builtin_amdgcn_mfma_f32_16x16x32_bf16(ah[i], bh[j], acc[i][j], 0, 0, 0);
        acc[i][j] = __builtin_amdgcn_mfma_f32_16x16x32_bf16(al[i], bh[j], acc[i][j], 0, 0, 0);
      }
    __builtin_amdgcn_s_barrier();
  }

  float bj[4];
#pragma unroll
  for (int j = 0; j < 4; ++j) bj[j] = bcat[n0 + wn + j * 16 + l16];
  bool isq = (n0 < 256);
#pragma unroll
  for (int i = 0; i < 4; ++i) {
    int rowb = row0 + wm + i * 16 + quad * 4;
#pragma unroll
    for (int r = 0; r < 4; ++r) {
      int grow = rowb + r;
      if (grow < N_NODES) {
        if (isq) {
          float* cp = qbuf + (size_t)grow * 256 + n0 + wn + l16;
#pragma unroll
          for (int j = 0; j < 4; ++j) cp[j * 16] = acc[i][j][r] + bj[j];
        } else {
          unsigned short* cp = kv + (size_t)grow * 512 + (n0 - 256) + wn + l16;
#pragma unroll
          for (int j = 0; j < 4; ++j) cp[j * 16] = f2bf(acc[i][j][r] + bj[j]);
        }
      }
    }
  }
}

// ---------------- per-dst-node edge attention ----------------
// v3: edge descriptors preloaded into registers (one coalesced load per node),
// 4-edge chunks with 2-deep A/B register pipeline -> 8 gathers in flight/wave.
#define LOAD1(pk, K, V, E)                                       \
  { const unsigned short* b_ = kv + (size_t)((pk) >> 3) * 512;   \
    K = ((const ushort4*)b_)[lane];                              \
    V = ((const ushort4*)(b_ + 256))[lane];                      \
    E = ((const float4*)(ete_s + ((pk) & 7) * 256))[lane]; }

#define EDGE1(K, V, E)                                                 \
  { float p_ = (bf2f(K.x) + E.x) * q4.x + (bf2f(K.y) + E.y) * q4.y +   \
               (bf2f(K.z) + E.z) * q4.z + (bf2f(K.w) + E.w) * q4.w;    \
    p_ += __shfl_xor(p_, 1); p_ += __shfl_xor(p_, 2);                  \
    p_ += __shfl_xor(p_, 4); p_ += __shfl_xor(p_, 8);                  \
    float e_ = __expf(p_ * 0.125f);                                    \
    lsum += e_;                                                        \
    ax = fmaf(e_, bf2f(V.x) + E.x, ax);                                \
    ay = fmaf(e_, bf2f(V.y) + E.y, ay);                                \
    az = fmaf(e_, bf2f(V.z) + E.z, az);                                \
    aw = fmaf(e_, bf2f(V.w) + E.w, aw); }

#define LOAD4(s, c)                                                    \
  { int p0_ = __shfl(mypk, (c));     int p1_ = __shfl(mypk, (c) + 1);  \
    int p2_ = __shfl(mypk, (c) + 2); int p3_ = __shfl(mypk, (c) + 3);  \
    LOAD1(p0_, k##s##0, v##s##0, e##s##0)                              \
    LOAD1(p1_, k##s##1, v##s##1, e##s##1)                              \
    LOAD1(p2_, k##s##2, v##s##2, e##s##2)                              \
    LOAD1(p3_, k##s##3, v##s##3, e##s##3) }

#define COMP4(s)                                                        \
    EDGE1(k##s##0, v##s##0, e##s##0) EDGE1(k##s##1, v##s##1, e##s##1)   \
    EDGE1(k##s##2, v##s##2, e##s##2) EDGE1(k##s##3, v##s##3, e##s##3)

__global__ __launch_bounds__(256) void k_attn(
    const float* __restrict__ qbuf, const unsigned short* __restrict__ kv,
    const int* __restrict__ rowstart, const int* __restrict__ packed,
    const float* __restrict__ Eemb_l,
    unsigned short* __restrict__ xhi, unsigned short* __restrict__ xlo) {
  __shared__ float ete_s[NETYPES * 256];
  int t = threadIdx.x;
#pragma unroll
  for (int i = 0; i < NETYPES; ++i) ete_s[i * 256 + t] = Eemb_l[i * 256 + t];
  __syncthreads();
  int lane = t & 63;
  int n = blockIdx.x * 4 + (t >> 6);
  float4 q4 = ((const float4*)(qbuf + (size_t)n * 256))[lane];
  int rs = rowstart[n], re = rowstart[n + 1];
  int deg = re - rs;

  float lsum = 0.f, ax = 0.f, ay = 0.f, az = 0.f, aw = 0.f;

  // one coalesced descriptor load per node (deg <= 64 fast path; mean deg = 8)
  int mypk = 0;
  if (deg > 0) mypk = packed[rs + (lane < deg ? lane : deg - 1)];

  int nfast = deg <= 64 ? deg : 64;
  int nc = nfast >> 2;

  ushort4 kA0, kA1, kA2, kA3, vA0, vA1, vA2, vA3;
  ushort4 kB0, kB1, kB2, kB3, vB0, vB1, vB2, vB3;
  float4 eA0, eA1, eA2, eA3, eB0, eB1, eB2, eB3;

  if (nc >= 1) LOAD4(A, 0)
  if (nc >= 2) LOAD4(B, 4)
  for (int cc = 0; cc < nc; ++cc) {
    if ((cc & 1) == 0) {
      COMP4(A)
      if (cc + 2 < nc) LOAD4(A, (cc + 2) * 4)
    } else {
      COMP4(B)
      if (cc + 2 < nc) LOAD4(B, (cc + 2) * 4)
    }
  }
  // tail within first 64 edges
  for (int i = nc * 4; i < nfast; ++i) {
    int pk_ = __shfl(mypk, i);
    ushort4 kh, vh; float4 e4;
    LOAD1(pk_, kh, vh, e4)
    EDGE1(kh, vh, e4)
  }
  // pathological tail (deg > 64): direct loads
  for (int i = rs + 64; i < re; ++i) {
    int pk_ = packed[i];
    ushort4 kh, vh; float4 e4;
    LOAD1(pk_, kh, vh, e4)
    EDGE1(kh, vh, e4)
  }

  float inv = 1.f / (lsum + 1e-16f);
  float4 o;
  o.x = ax * inv; o.y = ay * inv;
  o.z = az * inv; o.w = aw * inv;
  o.x = o.x > 0.f ? o.x : expm1f(o.x);
  o.y = o.y > 0.f ? o.y : expm1f(o.y);
  o.z = o.z > 0.f ? o.z : expm1f(o.z);
  o.w = o.w > 0.f ? o.w : expm1f(o.w);
  unsigned short h0 = f2bf(o.x), h1 = f2bf(o.y), h2 = f2bf(o.z), h3 = f2bf(o.w);
  ushort4 hv, lv;
  hv.x = h0; hv.y = h1; hv.z = h2; hv.w = h3;
  lv.x = f2bf(o.x - bf2f(h0)); lv.y = f2bf(o.y - bf2f(h1));
  lv.z = f2bf(o.z - bf2f(h2)); lv.w = f2bf(o.w - bf2f(h3));
  size_t base_o = (size_t)n * 256 + lane * 4;
  *(ushort4*)(xhi + base_o) = hv;
  *(ushort4*)(xlo + base_o) = lv;
}

// ---------------- parallel mean pool, stage 1 ----------------
__global__ __launch_bounds__(256) void k_pool_partial(
    const unsigned short* __restrict__ xhi, const unsigned short* __restrict__ xlo,
    const int* __restrict__ batch, float* __restrict__ gacc) {
  int t = threadIdx.x;
  int base = blockIdx.x * 128;
  int end = base + 128; if (end > N_NODES) end = N_NODES;
  __shared__ int bsh[128];
  if (t < 128 && base + t < N_NODES) bsh[t] = batch[base + t];
  __syncthreads();
  float acc = 0.f;
  int cur = bsh[0];
  for (int n = base; n < end; ++n) {
    int g = bsh[n - base];
    if (g != cur) {
      atomicAdd(&gacc[cur * 256 + t], acc);
      acc = 0.f; cur = g;
    }
    size_t idx = (size_t)n * 256 + t;
    acc += bf2f(xhi[idx]) + bf2f(xlo[idx]);
  }
  atomicAdd(&gacc[cur * 256 + t], acc);
}

// ---------------- GRU (h0=0) + FC ----------------
__device__ inline int lower_bound_dev(const int* a, int n, int val) {
  int lo = 0, hi = n;
  while (lo < hi) {
    int mid = (lo + hi) >> 1;
    if (a[mid] < val) lo = mid + 1; else hi = mid;
  }
  return lo;
}

__global__ __launch_bounds__(256) void k_gru_fc(
    const float* __restrict__ gacc, const int* __restrict__ batch,
    const float* __restrict__ W_ih, const float* __restrict__ b_ih,
    const float* __restrict__ b_hh, const float* __restrict__ W_fc,
    const float* __restrict__ b_fc, float* __restrict__ out) {
  __shared__ float gv[256];
  __shared__ float gates[192];
  __shared__ float h[64];
  int gr = blockIdx.x, t = threadIdx.x;
  int s0 = lower_bound_dev(batch, N_NODES, gr);
  int e0 = lower_bound_dev(batch, N_NODES, gr + 1);
  float c = (e0 > s0) ? (float)(e0 - s0) : 1.f;
  gv[t] = gacc[gr * 256 + t] / c;
  __syncthreads();
  if (t < 192) {
    const float* wr = W_ih + t * 256;
    float s = b_ih[t];
    for (int k = 0; k < 256; ++k) s = fmaf(gv[k], wr[k], s);
    gates[t] = s;
  }
  __syncthreads();
  if (t < 64) {
    float r  = 1.f / (1.f + expf(-(gates[t] + b_hh[t])));
    float z  = 1.f / (1.f + expf(-(gates[64 + t] + b_hh[64 + t])));
    float nn = tanhf(gates[128 + t] + r * b_hh[128 + t]);
    h[t] = (1.f - z) * nn;
  }
  __syncthreads();
  if (t < 2) {
    const float* wr = W_fc + t * 64;
    float s = b_fc[t];
    for (int k = 0; k < 64; ++k) s = fmaf(h[k], wr[k], s);
    out[gr * 2 + t] = s;
  }
}

extern "C" void kernel_launch(void* const* d_in, const int* in_sizes, int n_in,
                              void* d_out, int out_size, void* d_ws, size_t ws_size,
                              hipStream_t stream) {
  const float* x     = (const float*)d_in[0];
  const int* edge_index = (const int*)d_in[1];
  const int* batch   = (const int*)d_in[2];
  const int* etype   = (const int*)d_in[3];
  const float* Wq    = (const float*)d_in[4];
  const float* bq    = (const float*)d_in[5];
  const float* Wk    = (const float*)d_in[6];
  const float* bk    = (const float*)d_in[7];
  const float* Wv    = (const float*)d_in[8];
  const float* bv    = (const float*)d_in[9];
  const float* Eemb  = (const float*)d_in[10];
  const float* W_ih  = (const float*)d_in[11];
  const float* b_ih  = (const float*)d_in[12];
  const float* b_hh  = (const float*)d_in[14];
  const float* W_fc  = (const float*)d_in[15];
  const float* b_fc  = (const float*)d_in[16];
  float* out = (float*)d_out;

  const int* src = edge_index;
  const int* dst = edge_index + N_EDGES;

  float* qbuf  = (float*)d_ws;                             // N*256 f32
  float* gacc  = qbuf + (size_t)N_NODES * 256;             // 64*256
  float* bcat  = gacc + NGRAPHS * 256;                     // 3*768
  unsigned short* kv   = (unsigned short*)(bcat + NLAYERS * 768);  // N*512 bf16
  unsigned short* xhi  = kv + (size_t)N_NODES * 512;       // N*256
  unsigned short* xlo  = xhi + (size_t)N_NODES * 256;
  unsigned short* wthi = xlo + (size_t)N_NODES * 256;      // 3*768*256
  int* deg      = (int*)(wthi + (size_t)NLAYERS * 768 * 256);
  int* rowstart = deg + N_NODES;
  int* cursor   = rowstart + N_NODES + 1;
  int* packed   = cursor + N_NODES;

  hipMemsetAsync(deg, 0, N_NODES * sizeof(int), stream);
  hipMemsetAsync(gacc, 0, NGRAPHS * 256 * sizeof(float), stream);
  k_count_deg<<<(N_EDGES + 255) / 256, 256, 0, stream>>>(dst, deg);
  k_scan<<<1, 1024, 0, stream>>>(deg, rowstart, cursor);
  k_scatter<<<(N_EDGES + 255) / 256, 256, 0, stream>>>(src, dst, etype, cursor, packed);

  k_cvt_w<<<dim3(8, 24, 3), 256, 0, stream>>>(Wq, Wk, Wv, wthi);
  k_cvt_b<<<(NLAYERS * 768 + 255) / 256, 256, 0, stream>>>(bq, bk, bv, bcat);
  k_cvt_x<<<(N_NODES * 256 + 255) / 256, 256, 0, stream>>>(x, xhi, xlo);

  for (int l = 0; l < NLAYERS; ++l) {
    k_gemm_mfma<<<1440, 256, 0, stream>>>(
        xhi, xlo, wthi + (size_t)l * 768 * 256,
        bcat + l * 768, qbuf, kv);
    k_attn<<<N_NODES / 4, 256, 0, stream>>>(qbuf, kv, rowstart, packed,
                                            Eemb + (size_t)l * NETYPES * 256, xhi, xlo);
  }
  k_pool_partial<<<(N_NODES + 127) / 128, 256, 0, stream>>>(xhi, xlo, batch, gacc);
  k_gru_fc<<<NGRAPHS, 256, 0, stream>>>(gacc, batch, W_ih, b_ih, b_hh, W_fc, b_fc, out);
}

// Round 3
// 453.582 us; speedup vs baseline: 1.1046x; 1.1046x over previous
//
#include <hip/hip_runtime.h>
#include <math.h>

#define N_NODES 30000
#define N_EDGES 240000
#define DMODEL 256
#define NETYPES 8
#define NGRAPHS 64
#define NLAYERS 3

typedef __attribute__((ext_vector_type(8))) short short8;
typedef __attribute__((ext_vector_type(4))) float f32x4;

// ---- bf16 split helpers (round-to-nearest-even) ----
__device__ __forceinline__ unsigned short f2bf(float f) {
  union { float f; unsigned u; } v; v.f = f;
  unsigned r = v.u + 0x7FFF + ((v.u >> 16) & 1);
  return (unsigned short)(r >> 16);
}
__device__ __forceinline__ float bf2f(unsigned short h) {
  union { unsigned u; float f; } v; v.u = ((unsigned)h) << 16;
  return v.f;
}

__device__ __forceinline__ void async_g2l(const unsigned short* g, unsigned short* l) {
  __builtin_amdgcn_global_load_lds(
      (const __attribute__((address_space(1))) void*)g,
      (__attribute__((address_space(3))) void*)l, 16, 0, 0);
}

// 16-lane (intra-head) sum via DPP — replaces 4 chained ds_swizzle shfl_xor.
// Patterns: xor1, xor2 (quad_perm), ^7 (row_half_mirror, valid after quad sum),
// ^15 (row_mirror). Result lands in all 16 lanes of the row.
__device__ __forceinline__ float dpp_red_add(float x) {
  int v = __float_as_int(x);
  int t;
  t = __builtin_amdgcn_update_dpp(0, v, 0xB1, 0xF, 0xF, true);   // quad_perm [1,0,3,2]
  v = __float_as_int(__int_as_float(v) + __int_as_float(t));
  t = __builtin_amdgcn_update_dpp(0, v, 0x4E, 0xF, 0xF, true);   // quad_perm [2,3,0,1]
  v = __float_as_int(__int_as_float(v) + __int_as_float(t));
  t = __builtin_amdgcn_update_dpp(0, v, 0x141, 0xF, 0xF, true);  // row_half_mirror (^7)
  v = __float_as_int(__int_as_float(v) + __int_as_float(t));
  t = __builtin_amdgcn_update_dpp(0, v, 0x140, 0xF, 0xF, true);  // row_mirror (^15)
  v = __float_as_int(__int_as_float(v) + __int_as_float(t));
  return __int_as_float(v);
}

// ---------------- CSR build (by destination node) ----------------
__global__ void k_count_deg(const int* __restrict__ dst, int* __restrict__ deg) {
  int e = blockIdx.x * blockDim.x + threadIdx.x;
  if (e < N_EDGES) atomicAdd(&deg[dst[e]], 1);
}

__global__ __launch_bounds__(1024) void k_scan(const int* __restrict__ deg,
                                               int* __restrict__ rowstart,
                                               int* __restrict__ cursor) {
  const int C = 30;
  int tid = threadIdx.x;
  int base = tid * C;
  int vals[C];
  int sum = 0;
#pragma unroll
  for (int j = 0; j < C; ++j) {
    int idx = base + j;
    int v = (idx < N_NODES) ? deg[idx] : 0;
    vals[j] = sum;
    sum += v;
  }
  int lane = tid & 63, wv = tid >> 6;
  int s = sum;
#pragma unroll
  for (int off = 1; off < 64; off <<= 1) {
    int t2 = __shfl_up(s, off);
    if (lane >= off) s += t2;
  }
  __shared__ int wsum[16];
  if (lane == 63) wsum[wv] = s;
  __syncthreads();
  if (tid == 0) {
    int a = 0;
#pragma unroll
    for (int i = 0; i < 16; ++i) { int t2 = wsum[i]; wsum[i] = a; a += t2; }
    rowstart[N_NODES] = a;
  }
  __syncthreads();
  int texcl = wsum[wv] + (s - sum);
#pragma unroll
  for (int j = 0; j < C; ++j) {
    int idx = base + j;
    if (idx < N_NODES) {
      int p = texcl + vals[j];
      rowstart[idx] = p;
      cursor[idx]   = p;
    }
  }
}

__global__ void k_scatter(const int* __restrict__ src, const int* __restrict__ dst,
                          const int* __restrict__ etype, int* __restrict__ cursor,
                          int* __restrict__ packed) {
  int e = blockIdx.x * blockDim.x + threadIdx.x;
  if (e < N_EDGES) {
    int p = atomicAdd(&cursor[dst[e]], 1);
    packed[p] = src[e] * NETYPES + etype[e];
  }
}

// ---------------- weight transpose (coalesced, LDS tile), bf16 hi only ----------
__global__ __launch_bounds__(256) void k_cvt_w(
    const float* __restrict__ Wq, const float* __restrict__ Wk, const float* __restrict__ Wv,
    unsigned short* __restrict__ wthi) {
  __shared__ float tile[32][33];
  int k0 = blockIdx.x * 32;          // 0..224
  int n0g = blockIdx.y * 32;         // 0..736
  int l = blockIdx.z;
  int which = n0g >> 8;
  int col0 = n0g & 255;
  const float* W = (which == 0) ? Wq : ((which == 1) ? Wk : Wv);
  int c = threadIdx.x & 31, r = threadIdx.x >> 5;
#pragma unroll
  for (int rr = 0; rr < 4; ++rr) {
    int kk = r + rr * 8;
    tile[kk][c] = W[(size_t)l * 65536 + (size_t)(k0 + kk) * 256 + col0 + c];
  }
  __syncthreads();
  int kk = threadIdx.x & 31, nn0 = threadIdx.x >> 5;
#pragma unroll
  for (int rr = 0; rr < 4; ++rr) {
    int nn = nn0 + rr * 8;
    wthi[((size_t)l * 768 + n0g + nn) * 256 + k0 + kk] = f2bf(tile[kk][nn]);
  }
}

__global__ void k_cvt_b(const float* __restrict__ bq, const float* __restrict__ bk,
                        const float* __restrict__ bv, float* __restrict__ bcat) {
  int idx = blockIdx.x * 256 + threadIdx.x;
  if (idx >= NLAYERS * 768) return;
  int n = idx % 768, l = idx / 768;
  int which = n >> 8, col = n & 255;
  const float* b = (which == 0) ? bq : ((which == 1) ? bk : bv);
  bcat[idx] = b[l * 256 + col];
}

__global__ void k_cvt_x(const float* __restrict__ x, unsigned short* __restrict__ xhi,
                        unsigned short* __restrict__ xlo) {
  int i = blockIdx.x * 256 + threadIdx.x;
  if (i < N_NODES * 256) {
    float v = x[i];
    unsigned short h = f2bf(v);
    xhi[i] = h;
    xlo[i] = f2bf(v - bf2f(h));
  }
}

// ---------------- split-bf16 MFMA GEMM, 2-term (Ahi*Bhi + Alo*Bhi) ----------
// XCD-grouped swizzle (6 col-blocks of a row-tile share one XCD's L2) +
// double-buffered LDS with counted vmcnt (no vmcnt(0) drain inside the loop).
__global__ __launch_bounds__(256) void k_gemm_mfma(
    const unsigned short* __restrict__ Ahi, const unsigned short* __restrict__ Alo,
    const unsigned short* __restrict__ Bhi,
    const float* __restrict__ bcat, float* __restrict__ qbuf,
    unsigned short* __restrict__ kv) {
  __shared__ unsigned short smem[2 * 12288];

  int tid = threadIdx.x;
  int lane = tid & 63, wave = tid >> 6;
  int bx = blockIdx.x;
  int xcd = bx & 7, slot = bx >> 3;
  int rt = xcd + (slot / 6) * 8;
  if (rt >= 235) return;
  int row0 = rt * 128;
  int n0 = (slot % 6) * 128;
  int wm = (wave >> 1) * 64, wn = (wave & 1) * 64;
  int quad = lane >> 4, l16 = lane & 15;
  int chunk = lane & 3;
  int srow = wave * 32 + (lane >> 2);

  f32x4 acc[4][4];
#pragma unroll
  for (int i = 0; i < 4; ++i)
#pragma unroll
    for (int j = 0; j < 4; ++j) acc[i][j] = (f32x4)(0.f);

  auto STAGE = [&](int k0, int b) {
    unsigned short* s = smem + b * 12288;
#pragma unroll
    for (int j = 0; j < 2; ++j) {
      int r = srow + j * 16;
      int ldsoff = wave * 1024 + j * 512;
      int garA = row0 + r; if (garA >= N_NODES) garA = N_NODES - 1;
      size_t aoff = (size_t)garA * 256 + k0 + chunk * 8;
      async_g2l(Ahi + aoff, s + ldsoff);
      async_g2l(Alo + aoff, s + 4096 + ldsoff);
      size_t boff = (size_t)(n0 + r) * 256 + k0 + chunk * 8;
      async_g2l(Bhi + boff, s + 8192 + ldsoff);
    }
  };

  STAGE(0, 0);
#pragma unroll
  for (int k = 0; k < 8; ++k) {
    int cur = k & 1;
    if (k < 7) {
      STAGE((k + 1) * 32, cur ^ 1);
      asm volatile("s_waitcnt vmcnt(6)" ::: "memory");
    } else {
      asm volatile("s_waitcnt vmcnt(0)" ::: "memory");
    }
    __builtin_amdgcn_s_barrier();

    const unsigned short* sAhi = smem + cur * 12288;
    const unsigned short* sAlo = sAhi + 4096;
    const unsigned short* sBhi = sAhi + 8192;
    short8 ah[4], al[4], bh[4];
#pragma unroll
    for (int i = 0; i < 4; ++i) {
      int off = (wm + i * 16 + l16) * 32 + quad * 8;
      ah[i] = *(const short8*)(sAhi + off);
      al[i] = *(const short8*)(sAlo + off);
    }
#pragma unroll
    for (int j = 0; j < 4; ++j) {
      int off = (wn + j * 16 + l16) * 32 + quad * 8;
      bh[j] = *(const short8*)(sBhi + off);
    }
#pragma unroll
    for (int i = 0; i < 4; ++i)
#pragma unroll
      for (int j = 0; j < 4; ++j) {
        acc[i][j] = __builtin_amdgcn_mfma_f32_16x16x32_bf16(ah[i], bh[j], acc[i][j], 0, 0, 0);
        acc[i][j] = __builtin_amdgcn_mfma_f32_16x16x32_bf16(al[i], bh[j], acc[i][j], 0, 0, 0);
      }
    __builtin_amdgcn_s_barrier();
  }

  float bj[4];
#pragma unroll
  for (int j = 0; j < 4; ++j) bj[j] = bcat[n0 + wn + j * 16 + l16];
  bool isq = (n0 < 256);
#pragma unroll
  for (int i = 0; i < 4; ++i) {
    int rowb = row0 + wm + i * 16 + quad * 4;
#pragma unroll
    for (int r = 0; r < 4; ++r) {
      int grow = rowb + r;
      if (grow < N_NODES) {
        if (isq) {
          float* cp = qbuf + (size_t)grow * 256 + n0 + wn + l16;
#pragma unroll
          for (int j = 0; j < 4; ++j) cp[j * 16] = acc[i][j][r] + bj[j];
        } else {
          unsigned short* cp = kv + (size_t)grow * 512 + (n0 - 256) + wn + l16;
#pragma unroll
          for (int j = 0; j < 4; ++j) cp[j * 16] = f2bf(acc[i][j][r] + bj[j]);
        }
      }
    }
  }
}

// ---------------- per-dst-node edge attention, max-free softmax, 2x unroll ----------
// v4 = round-1 structure (32 VGPR, occupancy-friendly) + DPP 16-lane reduce
// (removes 4 chained DS-pipe shfl_xor per edge from the critical path).
__global__ __launch_bounds__(256) void k_attn(
    const float* __restrict__ qbuf, const unsigned short* __restrict__ kv,
    const int* __restrict__ rowstart, const int* __restrict__ packed,
    const float* __restrict__ Eemb_l,
    unsigned short* __restrict__ xhi, unsigned short* __restrict__ xlo) {
  __shared__ float ete_s[NETYPES * 256];
  int t = threadIdx.x;
#pragma unroll
  for (int i = 0; i < NETYPES; ++i) ete_s[i * 256 + t] = Eemb_l[i * 256 + t];
  __syncthreads();
  int lane = t & 63;
  int n = blockIdx.x * 4 + (t >> 6);
  float4 q4 = ((const float4*)(qbuf + (size_t)n * 256))[lane];
  int rs = rowstart[n], re = rowstart[n + 1];
  float l1 = 0.f, ax1 = 0.f, ay1 = 0.f, az1 = 0.f, aw1 = 0.f;
  float l2 = 0.f, ax2 = 0.f, ay2 = 0.f, az2 = 0.f, aw2 = 0.f;
  int i = rs;
  for (; i + 2 <= re; i += 2) {
    int pkA = packed[i], pkB = packed[i + 1];
    const unsigned short* baseA = kv + (size_t)(pkA >> 3) * 512;
    const unsigned short* baseB = kv + (size_t)(pkB >> 3) * 512;
    ushort4 kA = ((const ushort4*)baseA)[lane];
    ushort4 vA = ((const ushort4*)(baseA + 256))[lane];
    ushort4 kB = ((const ushort4*)baseB)[lane];
    ushort4 vB = ((const ushort4*)(baseB + 256))[lane];
    float4 eA = ((const float4*)(ete_s + (pkA & 7) * 256))[lane];
    float4 eB = ((const float4*)(ete_s + (pkB & 7) * 256))[lane];
    float pA = (bf2f(kA.x) + eA.x) * q4.x + (bf2f(kA.y) + eA.y) * q4.y +
               (bf2f(kA.z) + eA.z) * q4.z + (bf2f(kA.w) + eA.w) * q4.w;
    float pB = (bf2f(kB.x) + eB.x) * q4.x + (bf2f(kB.y) + eB.y) * q4.y +
               (bf2f(kB.z) + eB.z) * q4.z + (bf2f(kB.w) + eB.w) * q4.w;
    pA = dpp_red_add(pA);
    pB = dpp_red_add(pB);
    float e1 = __expf(pA * 0.125f);
    float e2 = __expf(pB * 0.125f);
    l1 += e1; l2 += e2;
    ax1 = fmaf(e1, bf2f(vA.x) + eA.x, ax1);
    ay1 = fmaf(e1, bf2f(vA.y) + eA.y, ay1);
    az1 = fmaf(e1, bf2f(vA.z) + eA.z, az1);
    aw1 = fmaf(e1, bf2f(vA.w) + eA.w, aw1);
    ax2 = fmaf(e2, bf2f(vB.x) + eB.x, ax2);
    ay2 = fmaf(e2, bf2f(vB.y) + eB.y, ay2);
    az2 = fmaf(e2, bf2f(vB.z) + eB.z, az2);
    aw2 = fmaf(e2, bf2f(vB.w) + eB.w, aw2);
  }
  if (i < re) {
    int pk = packed[i];
    const unsigned short* base = kv + (size_t)(pk >> 3) * 512;
    ushort4 kh = ((const ushort4*)base)[lane];
    ushort4 vh = ((const ushort4*)(base + 256))[lane];
    float4 e4 = ((const float4*)(ete_s + (pk & 7) * 256))[lane];
    float p = (bf2f(kh.x) + e4.x) * q4.x + (bf2f(kh.y) + e4.y) * q4.y +
              (bf2f(kh.z) + e4.z) * q4.z + (bf2f(kh.w) + e4.w) * q4.w;
    p = dpp_red_add(p);
    float e1 = __expf(p * 0.125f);
    l1 += e1;
    ax1 = fmaf(e1, bf2f(vh.x) + e4.x, ax1);
    ay1 = fmaf(e1, bf2f(vh.y) + e4.y, ay1);
    az1 = fmaf(e1, bf2f(vh.z) + e4.z, az1);
    aw1 = fmaf(e1, bf2f(vh.w) + e4.w, aw1);
  }
  float l = l1 + l2;
  float inv = 1.f / (l + 1e-16f);
  float4 o;
  o.x = (ax1 + ax2) * inv; o.y = (ay1 + ay2) * inv;
  o.z = (az1 + az2) * inv; o.w = (aw1 + aw2) * inv;
  o.x = o.x > 0.f ? o.x : expm1f(o.x);
  o.y = o.y > 0.f ? o.y : expm1f(o.y);
  o.z = o.z > 0.f ? o.z : expm1f(o.z);
  o.w = o.w > 0.f ? o.w : expm1f(o.w);
  unsigned short h0 = f2bf(o.x), h1 = f2bf(o.y), h2 = f2bf(o.z), h3 = f2bf(o.w);
  ushort4 hv, lv;
  hv.x = h0; hv.y = h1; hv.z = h2; hv.w = h3;
  lv.x = f2bf(o.x - bf2f(h0)); lv.y = f2bf(o.y - bf2f(h1));
  lv.z = f2bf(o.z - bf2f(h2)); lv.w = f2bf(o.w - bf2f(h3));
  size_t base_o = (size_t)n * 256 + lane * 4;
  *(ushort4*)(xhi + base_o) = hv;
  *(ushort4*)(xlo + base_o) = lv;
}

// ---------------- parallel mean pool, stage 1 ----------------
__global__ __launch_bounds__(256) void k_pool_partial(
    const unsigned short* __restrict__ xhi, const unsigned short* __restrict__ xlo,
    const int* __restrict__ batch, float* __restrict__ gacc) {
  int t = threadIdx.x;
  int base = blockIdx.x * 128;
  int end = base + 128; if (end > N_NODES) end = N_NODES;
  __shared__ int bsh[128];
  if (t < 128 && base + t < N_NODES) bsh[t] = batch[base + t];
  __syncthreads();
  float acc = 0.f;
  int cur = bsh[0];
  for (int n = base; n < end; ++n) {
    int g = bsh[n - base];
    if (g != cur) {
      atomicAdd(&gacc[cur * 256 + t], acc);
      acc = 0.f; cur = g;
    }
    size_t idx = (size_t)n * 256 + t;
    acc += bf2f(xhi[idx]) + bf2f(xlo[idx]);
  }
  atomicAdd(&gacc[cur * 256 + t], acc);
}

// ---------------- GRU (h0=0) + FC ----------------
__device__ inline int lower_bound_dev(const int* a, int n, int val) {
  int lo = 0, hi = n;
  while (lo < hi) {
    int mid = (lo + hi) >> 1;
    if (a[mid] < val) lo = mid + 1; else hi = mid;
  }
  return lo;
}

__global__ __launch_bounds__(256) void k_gru_fc(
    const float* __restrict__ gacc, const int* __restrict__ batch,
    const float* __restrict__ W_ih, const float* __restrict__ b_ih,
    const float* __restrict__ b_hh, const float* __restrict__ W_fc,
    const float* __restrict__ b_fc, float* __restrict__ out) {
  __shared__ float gv[256];
  __shared__ float gates[192];
  __shared__ float h[64];
  int gr = blockIdx.x, t = threadIdx.x;
  int s0 = lower_bound_dev(batch, N_NODES, gr);
  int e0 = lower_bound_dev(batch, N_NODES, gr + 1);
  float c = (e0 > s0) ? (float)(e0 - s0) : 1.f;
  gv[t] = gacc[gr * 256 + t] / c;
  __syncthreads();
  if (t < 192) {
    const float* wr = W_ih + t * 256;
    float s = b_ih[t];
    for (int k = 0; k < 256; ++k) s = fmaf(gv[k], wr[k], s);
    gates[t] = s;
  }
  __syncthreads();
  if (t < 64) {
    float r  = 1.f / (1.f + expf(-(gates[t] + b_hh[t])));
    float z  = 1.f / (1.f + expf(-(gates[64 + t] + b_hh[64 + t])));
    float nn = tanhf(gates[128 + t] + r * b_hh[128 + t]);
    h[t] = (1.f - z) * nn;
  }
  __syncthreads();
  if (t < 2) {
    const float* wr = W_fc + t * 64;
    float s = b_fc[t];
    for (int k = 0; k < 64; ++k) s = fmaf(h[k], wr[k], s);
    out[gr * 2 + t] = s;
  }
}

extern "C" void kernel_launch(void* const* d_in, const int* in_sizes, int n_in,
                              void* d_out, int out_size, void* d_ws, size_t ws_size,
                              hipStream_t stream) {
  const float* x     = (const float*)d_in[0];
  const int* edge_index = (const int*)d_in[1];
  const int* batch   = (const int*)d_in[2];
  const int* etype   = (const int*)d_in[3];
  const float* Wq    = (const float*)d_in[4];
  const float* bq    = (const float*)d_in[5];
  const float* Wk    = (const float*)d_in[6];
  const float* bk    = (const float*)d_in[7];
  const float* Wv    = (const float*)d_in[8];
  const float* bv    = (const float*)d_in[9];
  const float* Eemb  = (const float*)d_in[10];
  const float* W_ih  = (const float*)d_in[11];
  const float* b_ih  = (const float*)d_in[12];
  const float* b_hh  = (const float*)d_in[14];
  const float* W_fc  = (const float*)d_in[15];
  const float* b_fc  = (const float*)d_in[16];
  float* out = (float*)d_out;

  const int* src = edge_index;
  const int* dst = edge_index + N_EDGES;

  float* qbuf  = (float*)d_ws;                             // N*256 f32
  float* gacc  = qbuf + (size_t)N_NODES * 256;             // 64*256
  float* bcat  = gacc + NGRAPHS * 256;                     // 3*768
  unsigned short* kv   = (unsigned short*)(bcat + NLAYERS * 768);  // N*512 bf16
  unsigned short* xhi  = kv + (size_t)N_NODES * 512;       // N*256
  unsigned short* xlo  = xhi + (size_t)N_NODES * 256;
  unsigned short* wthi = xlo + (size_t)N_NODES * 256;      // 3*768*256
  int* deg      = (int*)(wthi + (size_t)NLAYERS * 768 * 256);
  int* rowstart = deg + N_NODES;
  int* cursor   = rowstart + N_NODES + 1;
  int* packed   = cursor + N_NODES;

  hipMemsetAsync(deg, 0, N_NODES * sizeof(int), stream);
  hipMemsetAsync(gacc, 0, NGRAPHS * 256 * sizeof(float), stream);
  k_count_deg<<<(N_EDGES + 255) / 256, 256, 0, stream>>>(dst, deg);
  k_scan<<<1, 1024, 0, stream>>>(deg, rowstart, cursor);
  k_scatter<<<(N_EDGES + 255) / 256, 256, 0, stream>>>(src, dst, etype, cursor, packed);

  k_cvt_w<<<dim3(8, 24, 3), 256, 0, stream>>>(Wq, Wk, Wv, wthi);
  k_cvt_b<<<(NLAYERS * 768 + 255) / 256, 256, 0, stream>>>(bq, bk, bv, bcat);
  k_cvt_x<<<(N_NODES * 256 + 255) / 256, 256, 0, stream>>>(x, xhi, xlo);

  for (int l = 0; l < NLAYERS; ++l) {
    k_gemm_mfma<<<1440, 256, 0, stream>>>(
        xhi, xlo, wthi + (size_t)l * 768 * 256,
        bcat + l * 768, qbuf, kv);
    k_attn<<<N_NODES / 4, 256, 0, stream>>>(qbuf, kv, rowstart, packed,
                                            Eemb + (size_t)l * NETYPES * 256, xhi, xlo);
  }
  k_pool_partial<<<(N_NODES + 127) / 128, 256, 0, stream>>>(xhi, xlo, batch, gacc);
  k_gru_fc<<<NGRAPHS, 256, 0, stream>>>(gacc, batch, W_ih, b_ih, b_hh, W_fc, b_fc, out);
}